// Round 16
// baseline (533.294 us; speedup 1.0000x reference)
//
#include <hip/hip_runtime.h>
#include <math.h>

#ifndef M_PI
#define M_PI 3.14159265358979323846
#endif

#define BB 1024
#define SIZE 512
#define NF 128
#define WIDTH 32
#define TOTAL (SIZE*NF)

// DPP-based unsigned max reduce step (VALU latency, no LDS pipe)
#define DPP_UMAX(x, ctrl, rmask) { \
    unsigned _t = (unsigned)__builtin_amdgcn_update_dpp(0, (int)(x), (ctrl), (rmask), 0xf, false); \
    if (_t > (x)) (x) = _t; }

__device__ __forceinline__ float readlanef(float x, int l) {
    return __int_as_float(__builtin_amdgcn_readlane(__float_as_int(x), l));
}

// fast reciprocal: v_rcp_f32 + 1 Newton step (~1 ulp)
__device__ __forceinline__ float frcp_fast(float x) {
    float r = __builtin_amdgcn_rcpf(x);
    return r * (2.0f - x * r);
}

// ---------------------------------------------------------------------------
// Kernel 1: per-sample FNO frontend -> pooled[b][32], pos[r][b] (gather map)
// ---------------------------------------------------------------------------
__global__ __launch_bounds__(256) void fno_pooled_kernel(
    const int*   __restrict__ n,
    const float* __restrict__ lift_W,
    const float* __restrict__ lift_b,
    const float* __restrict__ spec_Wr,
    const float* __restrict__ spec_Wi,
    const float* __restrict__ pw_W,
    const float* __restrict__ pw_b,
    float* __restrict__ pooled_g,
    signed char* __restrict__ pos_g)
{
    __shared__ float nf[SIZE];
    __shared__ float c32[32], s32[32];
    __shared__ float Gre[16], Gim[16];
    __shared__ float wsum[4][32];
    __shared__ float Arr[WIDTH][16], Aii[WIDTH][16];
    __shared__ float lowr[WIDTH][16], lowi[WIDTH][16];
    __shared__ float pwl[WIDTH], cb0[WIDTH];
    __shared__ float Brr[WIDTH], Bii[WIDTH];

    const int b = blockIdx.x;
    const int t = threadIdx.x;
    const int lane = t & 63;
    const int wave = t >> 6;

    if (t < 32) {
        float ang = (float)t * (2.0f * (float)M_PI / 32.0f);
        c32[t] = cosf(ang);
        s32[t] = sinf(ang);
    }
    for (int p = t; p < SIZE; p += 256) nf[p] = (float)n[b*SIZE + p];
    __syncthreads();

    if (wave == 0) {
        int base = 0;
        for (int c = 0; c < 8; ++c) {
            int p = c*64 + lane;
            bool occ = (nf[p] != 0.0f);
            unsigned long long mask = __ballot(occ);
            int prefix = __popcll(mask & ((1ull << lane) - 1ull));
            int pos = base + prefix;
            pos_g[(size_t)p*BB + b] = (occ && pos < NF) ? (signed char)pos : (signed char)-1;
            base += __popcll(mask);
        }
    }

    float gre[16], gim[16];
    #pragma unroll
    for (int m = 0; m < 16; ++m) { gre[m] = 0.f; gim[m] = 0.f; }
    for (int p = t; p < SIZE; p += 256) {
        float v = nf[p];
        int x = p >> 4, y = p & 15;
        #pragma unroll
        for (int kx = 0; kx < 4; ++kx) {
            #pragma unroll
            for (int ky = 0; ky < 4; ++ky) {
                int idx = (kx*x + 2*ky*y) & 31;
                gre[kx*4+ky] += v * c32[idx];
                gim[kx*4+ky] -= v * s32[idx];
            }
        }
    }
    #pragma unroll
    for (int m = 0; m < 16; ++m) {
        for (int off = 32; off > 0; off >>= 1) {
            gre[m] += __shfl_xor(gre[m], off, 64);
            gim[m] += __shfl_xor(gim[m], off, 64);
        }
    }
    if (lane == 0) {
        #pragma unroll
        for (int m = 0; m < 16; ++m) { wsum[wave][m] = gre[m]; wsum[wave][16+m] = gim[m]; }
    }
    __syncthreads();
    if (t < 32) {
        float s = wsum[0][t] + wsum[1][t] + wsum[2][t] + wsum[3][t];
        if (t < 16) Gre[t] = s; else Gim[t-16] = s;
    }

    for (int idx = t; idx < 512; idx += 256) {
        int o = idx >> 4, m = idx & 15;
        float ar = 0.f, ai = 0.f;
        for (int ii = 0; ii < WIDTH; ++ii) {
            float lw = lift_W[ii];
            ar += lw * spec_Wr[ii*512 + o*16 + m];
            ai += lw * spec_Wi[ii*512 + o*16 + m];
        }
        Arr[o][m] = ar; Aii[o][m] = ai;
    }
    if (t < 32) {
        float br = 0.f, bi = 0.f, pl = 0.f, cb = 0.f;
        for (int ii = 0; ii < WIDTH; ++ii) {
            float lb = lift_b[ii];
            br += lb * spec_Wr[ii*512 + t*16 + 0];
            bi += lb * spec_Wi[ii*512 + t*16 + 0];
            pl += lift_W[ii] * pw_W[ii*WIDTH + t];
            cb += lb * pw_W[ii*WIDTH + t];
        }
        Brr[t] = br; Bii[t] = bi;
        pwl[t] = pl;
        cb0[t] = cb + pw_b[t];
    }
    __syncthreads();

    for (int idx = t; idx < 512; idx += 256) {
        int o = idx >> 4, m = idx & 15;
        float gr = Gre[m], gi = Gim[m];
        float ar = Arr[o][m], ai = Aii[o][m];
        float lr = gr*ar - gi*ai;
        float li = gr*ai + gi*ar;
        if (m == 0) { lr += 512.f * Brr[o]; li += 512.f * Bii[o]; }
        lowr[o][m] = lr; lowi[o][m] = li;
    }
    __syncthreads();

    const int o  = t >> 3;
    const int xg = t & 7;
    const float plo = pwl[o], cbo = cb0[o];
    float acc = 0.f;
    const float inv32 = 1.0f/32.0f, inv16 = 1.0f/16.0f;
    for (int xi = 0; xi < 4; ++xi) {
        int x = xg*4 + xi;
        float Tre[4], Tim[4];
        #pragma unroll
        for (int ky = 0; ky < 4; ++ky) { Tre[ky] = 0.f; Tim[ky] = 0.f; }
        #pragma unroll
        for (int kx = 0; kx < 4; ++kx) {
            int idx = (kx*x) & 31;
            float c = c32[idx], s = s32[idx];
            #pragma unroll
            for (int ky = 0; ky < 4; ++ky) {
                float lr = lowr[o][kx*4+ky], li = lowi[o][kx*4+ky];
                Tre[ky] += lr*c - li*s;
                Tim[ky] += lr*s + li*c;
            }
        }
        #pragma unroll
        for (int ky = 0; ky < 4; ++ky) { Tre[ky] *= inv32; Tim[ky] *= inv32; }
        for (int y = 0; y < 16; ++y) {
            float hsv = Tre[0];
            #pragma unroll
            for (int ky = 1; ky < 4; ++ky) {
                int idx = (2*ky*y) & 31;
                hsv += 2.f*(Tre[ky]*c32[idx] - Tim[ky]*s32[idx]);
            }
            hsv *= inv16;
            float z = hsv + nf[x*16 + y]*plo + cbo;
            acc += tanhf(z);
        }
    }
    acc += __shfl_down(acc, 4, 8);
    acc += __shfl_down(acc, 2, 8);
    acc += __shfl_down(acc, 1, 8);
    if ((t & 7) == 0) pooled_g[b*WIDTH + o] = acc * (1.0f/512.0f);
}

// ---------------------------------------------------------------------------
// Kernel 2: r-major gathered build, ONE block per row r (512 blocks).
// wj (proj_W segment) loaded once per r -> proj_W traffic 32 MB (was 128).
// pooled staged in 4 tiles of 256 samples (L2-resident source).
// ---------------------------------------------------------------------------
__global__ __launch_bounds__(256) void build_kernel(
    const float* __restrict__ M_base,
    const float* __restrict__ proj_W,
    const float* __restrict__ proj_b,
    const float* __restrict__ pooled_g,
    const signed char* __restrict__ pos_g,
    float* __restrict__ A_ws)
{
    __shared__ float pooled_l[256*WIDTH];   // 32 KB
    __shared__ signed char posl[256];

    const int r   = blockIdx.x;
    const int t   = threadIdx.x;
    const int j   = t & 127;
    const int sub = t >> 7;

    float wj[WIDTH];
    #pragma unroll
    for (int o = 0; o < WIDTH; ++o) wj[o] = proj_W[(size_t)o*TOTAL + r*NF + j];
    const float base = M_base[r*NF + j] + proj_b[r*NF + j];

    for (int tile = 0; tile < 4; ++tile) {
        const int b0 = tile * 256;
        __syncthreads();   // previous tile fully consumed
        {
            const float4* src = (const float4*)(pooled_g + (size_t)b0*WIDTH);
            float4* dst = (float4*)pooled_l;
            for (int idx = t; idx < 256*WIDTH/4; idx += 256) dst[idx] = src[idx];
            if (t < 64) ((int*)posl)[t] = ((const int*)(pos_g + (size_t)r*BB + b0))[t];
        }
        __syncthreads();

        for (int bb = sub; bb < 256; bb += 2) {
            int pos = posl[bb];
            if (pos < 0) continue;
            const float4* pl4 = (const float4*)&pooled_l[bb*WIDTH];
            float4 p0 = pl4[0], p1 = pl4[1], p2 = pl4[2], p3 = pl4[3];
            float4 p4 = pl4[4], p5 = pl4[5], p6 = pl4[6], p7 = pl4[7];
            float acc = base;
            acc += p0.x*wj[0]  + p0.y*wj[1]  + p0.z*wj[2]  + p0.w*wj[3];
            acc += p1.x*wj[4]  + p1.y*wj[5]  + p1.z*wj[6]  + p1.w*wj[7];
            acc += p2.x*wj[8]  + p2.y*wj[9]  + p2.z*wj[10] + p2.w*wj[11];
            acc += p3.x*wj[12] + p3.y*wj[13] + p3.z*wj[14] + p3.w*wj[15];
            acc += p4.x*wj[16] + p4.y*wj[17] + p4.z*wj[18] + p4.w*wj[19];
            acc += p5.x*wj[20] + p5.y*wj[21] + p5.z*wj[22] + p5.w*wj[23];
            acc += p6.x*wj[24] + p6.y*wj[25] + p6.z*wj[26] + p6.w*wj[27];
            acc += p7.x*wj[28] + p7.y*wj[29] + p7.z*wj[30] + p7.w*wj[31];
            A_ws[((size_t)(b0+bb)*NF + pos)*NF + j] = acc;
        }
    }
}

// ---------------------------------------------------------------------------
// Kernel 3: rank-8 LU, A in registers, all-wave redundant pivot, ONE barrier
// per panel. Publish phase stores PRE-update values (pcol/coef/Raw, all
// double-buffered); the next panel's chain applies the rank-8 correction
// itself (bitwise-identical accumulation order -> consistent with Areg path).
// Cross-wave safety: every concurrent read/write pair targets opposite
// buffers; barrier(p) orders all chain(p) reads before (p+1) publishes.
// Output planar: out[b] = logabs, out[BB+b] = 0 or pi.
// ---------------------------------------------------------------------------
__global__ __launch_bounds__(512) void lu_kernel(
    const float* __restrict__ A_ws,
    float* __restrict__ out)
{
    __shared__ __align__(16) float pcolA[2][128*4];   // even panel-col group
    __shared__ __align__(16) float pcolB[2][128*4];   // odd panel-col group
    __shared__ __align__(16) float Raw[2][8*128];     // pivot rows (pre-update)
    __shared__ __align__(16) float coefA[2][128*4];   // coefs s=0..3 per row
    __shared__ __align__(16) float coefB[2][128*4];   // coefs s=4..7 per row
    __shared__ float pvbuf[128];
    __shared__ int   pivseq[128];

    const int t = threadIdx.x;
    const int l = t & 63;
    const int w = t >> 6;
    const int half = w & 1;
    const int q = w >> 1;
    const int i = l + 64*half;
    const int b = blockIdx.x;

    float4 Areg[8];
    {
        const float4* src = (const float4*)(A_ws + (size_t)b*(NF*NF) + i*NF + q*32);
        #pragma unroll
        for (int g = 0; g < 8; ++g) Areg[g] = src[g];
        if (q == 0) {
            *((float4*)&pcolA[0][i*4]) = Areg[0];
            *((float4*)&pcolB[0][i*4]) = Areg[1];
        }
    }
    bool done_i = false;
    bool done0 = false, done1 = false;   // per-lane retire masks (identical in all waves)
    __syncthreads();

    for (int p = 0; p < 16; ++p) {
        const int cb = p & 1;

        // ---------- chain(p): all waves, redundant ----------
        float4 a0v = *((const float4*)&pcolA[cb][l*4]);
        float4 b0v = *((const float4*)&pcolB[cb][l*4]);
        float4 a1v = *((const float4*)&pcolA[cb][l*4 + 256]);
        float4 b1v = *((const float4*)&pcolB[cb][l*4 + 256]);
        float v0[8] = { a0v.x,a0v.y,a0v.z,a0v.w, b0v.x,b0v.y,b0v.z,b0v.w };
        float v1[8] = { a1v.x,a1v.y,a1v.z,a1v.w, b1v.x,b1v.y,b1v.z,b1v.w };

        if (p > 0) {
            // correction: apply update(p-1) to the loaded pre-update columns
            const int pb = cb ^ 1;
            const float4 c0a = *((const float4*)&coefA[pb][l*4]);
            const float4 c0b = *((const float4*)&coefB[pb][l*4]);
            const float4 c1a = *((const float4*)&coefA[pb][l*4 + 256]);
            const float4 c1b = *((const float4*)&coefB[pb][l*4 + 256]);
            const float c0[8] = { c0a.x,c0a.y,c0a.z,c0a.w, c0b.x,c0b.y,c0b.z,c0b.w };
            const float c1[8] = { c1a.x,c1a.y,c1a.z,c1a.w, c1b.x,c1b.y,c1b.z,c1b.w };
            const int G0 = 2*p, G1 = 2*p + 1;
            #pragma unroll
            for (int s = 0; s < 8; ++s) {
                const float4 r0 = *((const float4*)&Raw[pb][s*128 + G0*4]);
                const float4 r1 = *((const float4*)&Raw[pb][s*128 + G1*4]);
                v0[0] += c0[s]*r0.x; v0[1] += c0[s]*r0.y; v0[2] += c0[s]*r0.z; v0[3] += c0[s]*r0.w;
                v0[4] += c0[s]*r1.x; v0[5] += c0[s]*r1.y; v0[6] += c0[s]*r1.z; v0[7] += c0[s]*r1.w;
                v1[0] += c1[s]*r0.x; v1[1] += c1[s]*r0.y; v1[2] += c1[s]*r0.z; v1[3] += c1[s]*r0.w;
                v1[4] += c1[s]*r1.x; v1[5] += c1[s]*r1.y; v1[6] += c1[s]*r1.z; v1[7] += c1[s]*r1.w;
            }
        }

        float lr0[8], lr1[8];
        int   prreg[8];
        #pragma unroll
        for (int k = 0; k < 8; ++k) {
            unsigned aa0 = __float_as_uint(v0[k]) & 0x7fffffffu;
            unsigned aa1 = __float_as_uint(v1[k]) & 0x7fffffffu;
            unsigned key0 = done0 ? 0u : ((aa0 & 0xffffff80u) | (unsigned)l);
            unsigned key1 = done1 ? 0u : ((aa1 & 0xffffff80u) | (unsigned)(l + 64));
            unsigned key = (key1 > key0) ? key1 : key0;
            DPP_UMAX(key, 0x111, 0xf);   // row_shr:1
            DPP_UMAX(key, 0x112, 0xf);   // row_shr:2
            DPP_UMAX(key, 0x114, 0xf);   // row_shr:4
            DPP_UMAX(key, 0x118, 0xf);   // row_shr:8
            DPP_UMAX(key, 0x142, 0xa);   // row_bcast:15
            DPP_UMAX(key, 0x143, 0xc);   // row_bcast:31
            const unsigned best = (unsigned)__builtin_amdgcn_readlane((int)key, 63);
            const int row = (int)(best & 127u);
            const int lw  = row & 63;
            const bool lowh = (row < 64);
            const float pv = lowh ? readlanef(v0[k], lw) : readlanef(v1[k], lw);
            prreg[k] = row;
            const float inv = frcp_fast(pv);
            float l0 = (done0 || row == l)      ? 0.f : v0[k] * inv;
            float l1 = (done1 || row == l + 64) ? 0.f : v1[k] * inv;
            lr0[k] = l0; lr1[k] = l1;
            if (row == l)      done0 = true;
            if (row == l + 64) done1 = true;
            #pragma unroll
            for (int j = 0; j < 8; ++j) if (j > k) {
                float ukj = lowh ? readlanef(v0[j], lw) : readlanef(v1[j], lw);
                v0[j] -= l0 * ukj;
                v1[j] -= l1 * ukj;
            }
            if (w == 0 && l == 0) { pivseq[8*p+k] = row; pvbuf[8*p+k] = pv; }
        }

        // ---------- per-thread coefs for OWN row (back-sub, Lt fused) ----------
        float cs[8];
        {
            float lm[8];
            #pragma unroll
            for (int s = 0; s < 8; ++s) lm[s] = half ? lr1[s] : lr0[s];
            #pragma unroll
            for (int s2 = 7; s2 >= 0; --s2) {
                float acc = -lm[s2];
                #pragma unroll
                for (int sp = 7; sp > 0; --sp) if (sp > s2) {
                    float Lt = (prreg[sp] < 64) ? readlanef(lr0[s2], prreg[sp])
                                                : readlanef(lr1[s2], prreg[sp] - 64);
                    acc -= cs[sp] * Lt;
                }
                cs[s2] = acc;
            }
        }

        // ---------- publish (pre-update values), all double-buffered ----------
        int fp = -1;
        #pragma unroll
        for (int s = 0; s < 8; ++s) if (i == prreg[s]) fp = s;
        if (fp >= 0) {
            #pragma unroll
            for (int g = 0; g < 8; ++g)
                *((float4*)&Raw[cb][fp*128 + (q*8 + g)*4]) = Areg[g];
        }
        if (q == 0) {   // coef store for next chain's correction (rows i and i)
            *((float4*)&coefA[cb][i*4]) = make_float4(cs[0], cs[1], cs[2], cs[3]);
            *((float4*)&coefB[cb][i*4]) = make_float4(cs[4], cs[5], cs[6], cs[7]);
        }
        if (p < 15) {   // pre-update copy of next panel's columns
            const int nG0 = 2*p + 2;
            if (q == (nG0 >> 3)) {
                const int ge = nG0 & 7;
                float4 ve = Areg[0], vo = Areg[1];
                #pragma unroll
                for (int g = 0; g < 8; ++g) {
                    if (g == ge)     ve = Areg[g];
                    if (g == ge + 1) vo = Areg[g];
                }
                *((float4*)&pcolA[cb ^ 1][i*4]) = ve;
                *((float4*)&pcolB[cb ^ 1][i*4]) = vo;
            }
        }
        __syncthreads();   // the ONLY barrier per panel

        // ---------- update(p) on own registers ----------
        if (fp >= 0) {
            done_i = true;   // retired; trailing values never read again
        } else if (!done_i) {
            #pragma unroll
            for (int g = 0; g < 8; ++g) {
                const int G = q*8 + g;
                if (G > 2*p + 1) {
                    const int cbase = G*4;
                    float4 own = Areg[g];
                    #pragma unroll
                    for (int s = 0; s < 8; ++s) {
                        const float4 rv = *((const float4*)&Raw[cb][s*128 + cbase]);
                        own.x += cs[s]*rv.x; own.y += cs[s]*rv.y;
                        own.z += cs[s]*rv.z; own.w += cs[s]*rv.w;
                    }
                    Areg[g] = own;
                }
            }
        }
        // no barrier: next chain reads only pre-published opposite buffers
    }

    // ---------- logabs + sign (wave 0; pvbuf/pivseq self-written) ----------
    if (w == 0) {
        float d0 = pvbuf[l], d1 = pvbuf[l + 64];
        int   ps0 = pivseq[l], ps1 = pivseq[l + 64];
        float ls = logf(fabsf(d0)) + logf(fabsf(d1));
        int neg = ((d0 < 0.f) ? 1 : 0) ^ ((d1 < 0.f) ? 1 : 0);
        #pragma unroll
        for (int off = 32; off > 0; off >>= 1) {
            ls  += __shfl_xor(ls,  off, 64);
            neg ^= __shfl_xor(neg, off, 64);
        }
        unsigned long long vis0 = 0ull, vis1 = 0ull;
        int trans = 0;
        for (int k = 0; k < 128; ++k) {
            bool vk = (k < 64) ? ((vis0 >> k) & 1ull) : ((vis1 >> (k - 64)) & 1ull);
            if (!vk) {
                int j = k, len = 0;
                while (true) {
                    bool vj = (j < 64) ? ((vis0 >> j) & 1ull) : ((vis1 >> (j - 64)) & 1ull);
                    if (vj) break;
                    if (j < 64) vis0 |= (1ull << j); else vis1 |= (1ull << (j - 64));
                    j = (j < 64) ? __builtin_amdgcn_readlane(ps0, j)
                                 : __builtin_amdgcn_readlane(ps1, j - 64);
                    ++len;
                }
                trans += len - 1;
            }
        }
        if (l == 0) {
            int parity = (neg ^ (trans & 1)) & 1;
            out[b]      = ls;
            out[BB + b] = parity ? (float)M_PI : 0.0f;
        }
    }
}

// ---------------------------------------------------------------------------
extern "C" void kernel_launch(void* const* d_in, const int* in_sizes, int n_in,
                              void* d_out, int out_size, void* d_ws, size_t ws_size,
                              hipStream_t stream) {
    const int*   n       = (const int*)  d_in[0];
    const float* M_base  = (const float*)d_in[1];
    const float* lift_W  = (const float*)d_in[2];
    const float* lift_b  = (const float*)d_in[3];
    const float* spec_Wr = (const float*)d_in[4];
    const float* spec_Wi = (const float*)d_in[5];
    const float* pw_W    = (const float*)d_in[6];
    const float* pw_b    = (const float*)d_in[7];
    const float* proj_W  = (const float*)d_in[8];
    const float* proj_b  = (const float*)d_in[9];

    // ws layout: pooled 128KB | pos 512KB | (align 1MB) A_ws 64MB
    float*       pooled = (float*)d_ws;
    signed char* pos    = (signed char*)((char*)d_ws + 128*1024);
    float*       A_ws   = (float*)((char*)d_ws + (1 << 20));

    fno_pooled_kernel<<<BB, 256, 0, stream>>>(n, lift_W, lift_b, spec_Wr, spec_Wi,
                                              pw_W, pw_b, pooled, pos);
    build_kernel<<<SIZE, 256, 0, stream>>>(M_base, proj_W, proj_b, pooled, pos, A_ws);
    lu_kernel<<<BB, 512, 0, stream>>>(A_ws, (float*)d_out);
}

// Round 17
// 303.255 us; speedup vs baseline: 1.7586x; 1.7586x over previous
//
#include <hip/hip_runtime.h>
#include <math.h>

#ifndef M_PI
#define M_PI 3.14159265358979323846
#endif

#define BB 1024
#define SIZE 512
#define NF 128
#define WIDTH 32
#define TOTAL (SIZE*NF)

// DPP-based unsigned max reduce step (VALU latency, no LDS pipe)
#define DPP_UMAX(x, ctrl, rmask) { \
    unsigned _t = (unsigned)__builtin_amdgcn_update_dpp(0, (int)(x), (ctrl), (rmask), 0xf, false); \
    if (_t > (x)) (x) = _t; }

__device__ __forceinline__ float readlanef(float x, int l) {
    return __int_as_float(__builtin_amdgcn_readlane(__float_as_int(x), l));
}

// fast reciprocal: v_rcp_f32 + 1 Newton step (~1 ulp)
__device__ __forceinline__ float frcp_fast(float x) {
    float r = __builtin_amdgcn_rcpf(x);
    return r * (2.0f - x * r);
}

// ---------------------------------------------------------------------------
// Kernel 1: per-sample FNO frontend -> pooled[b][32], pos[r][b] (gather map)
// ---------------------------------------------------------------------------
__global__ __launch_bounds__(256) void fno_pooled_kernel(
    const int*   __restrict__ n,
    const float* __restrict__ lift_W,
    const float* __restrict__ lift_b,
    const float* __restrict__ spec_Wr,
    const float* __restrict__ spec_Wi,
    const float* __restrict__ pw_W,
    const float* __restrict__ pw_b,
    float* __restrict__ pooled_g,
    signed char* __restrict__ pos_g)
{
    __shared__ float nf[SIZE];
    __shared__ float c32[32], s32[32];
    __shared__ float Gre[16], Gim[16];
    __shared__ float wsum[4][32];
    __shared__ float Arr[WIDTH][16], Aii[WIDTH][16];
    __shared__ float lowr[WIDTH][16], lowi[WIDTH][16];
    __shared__ float pwl[WIDTH], cb0[WIDTH];
    __shared__ float Brr[WIDTH], Bii[WIDTH];

    const int b = blockIdx.x;
    const int t = threadIdx.x;
    const int lane = t & 63;
    const int wave = t >> 6;

    if (t < 32) {
        float ang = (float)t * (2.0f * (float)M_PI / 32.0f);
        c32[t] = cosf(ang);
        s32[t] = sinf(ang);
    }
    for (int p = t; p < SIZE; p += 256) nf[p] = (float)n[b*SIZE + p];
    __syncthreads();

    if (wave == 0) {
        int base = 0;
        for (int c = 0; c < 8; ++c) {
            int p = c*64 + lane;
            bool occ = (nf[p] != 0.0f);
            unsigned long long mask = __ballot(occ);
            int prefix = __popcll(mask & ((1ull << lane) - 1ull));
            int pos = base + prefix;
            pos_g[(size_t)p*BB + b] = (occ && pos < NF) ? (signed char)pos : (signed char)-1;
            base += __popcll(mask);
        }
    }

    float gre[16], gim[16];
    #pragma unroll
    for (int m = 0; m < 16; ++m) { gre[m] = 0.f; gim[m] = 0.f; }
    for (int p = t; p < SIZE; p += 256) {
        float v = nf[p];
        int x = p >> 4, y = p & 15;
        #pragma unroll
        for (int kx = 0; kx < 4; ++kx) {
            #pragma unroll
            for (int ky = 0; ky < 4; ++ky) {
                int idx = (kx*x + 2*ky*y) & 31;
                gre[kx*4+ky] += v * c32[idx];
                gim[kx*4+ky] -= v * s32[idx];
            }
        }
    }
    #pragma unroll
    for (int m = 0; m < 16; ++m) {
        for (int off = 32; off > 0; off >>= 1) {
            gre[m] += __shfl_xor(gre[m], off, 64);
            gim[m] += __shfl_xor(gim[m], off, 64);
        }
    }
    if (lane == 0) {
        #pragma unroll
        for (int m = 0; m < 16; ++m) { wsum[wave][m] = gre[m]; wsum[wave][16+m] = gim[m]; }
    }
    __syncthreads();
    if (t < 32) {
        float s = wsum[0][t] + wsum[1][t] + wsum[2][t] + wsum[3][t];
        if (t < 16) Gre[t] = s; else Gim[t-16] = s;
    }

    for (int idx = t; idx < 512; idx += 256) {
        int o = idx >> 4, m = idx & 15;
        float ar = 0.f, ai = 0.f;
        for (int ii = 0; ii < WIDTH; ++ii) {
            float lw = lift_W[ii];
            ar += lw * spec_Wr[ii*512 + o*16 + m];
            ai += lw * spec_Wi[ii*512 + o*16 + m];
        }
        Arr[o][m] = ar; Aii[o][m] = ai;
    }
    if (t < 32) {
        float br = 0.f, bi = 0.f, pl = 0.f, cb = 0.f;
        for (int ii = 0; ii < WIDTH; ++ii) {
            float lb = lift_b[ii];
            br += lb * spec_Wr[ii*512 + t*16 + 0];
            bi += lb * spec_Wi[ii*512 + t*16 + 0];
            pl += lift_W[ii] * pw_W[ii*WIDTH + t];
            cb += lb * pw_W[ii*WIDTH + t];
        }
        Brr[t] = br; Bii[t] = bi;
        pwl[t] = pl;
        cb0[t] = cb + pw_b[t];
    }
    __syncthreads();

    for (int idx = t; idx < 512; idx += 256) {
        int o = idx >> 4, m = idx & 15;
        float gr = Gre[m], gi = Gim[m];
        float ar = Arr[o][m], ai = Aii[o][m];
        float lr = gr*ar - gi*ai;
        float li = gr*ai + gi*ar;
        if (m == 0) { lr += 512.f * Brr[o]; li += 512.f * Bii[o]; }
        lowr[o][m] = lr; lowi[o][m] = li;
    }
    __syncthreads();

    const int o  = t >> 3;
    const int xg = t & 7;
    const float plo = pwl[o], cbo = cb0[o];
    float acc = 0.f;
    const float inv32 = 1.0f/32.0f, inv16 = 1.0f/16.0f;
    for (int xi = 0; xi < 4; ++xi) {
        int x = xg*4 + xi;
        float Tre[4], Tim[4];
        #pragma unroll
        for (int ky = 0; ky < 4; ++ky) { Tre[ky] = 0.f; Tim[ky] = 0.f; }
        #pragma unroll
        for (int kx = 0; kx < 4; ++kx) {
            int idx = (kx*x) & 31;
            float c = c32[idx], s = s32[idx];
            #pragma unroll
            for (int ky = 0; ky < 4; ++ky) {
                float lr = lowr[o][kx*4+ky], li = lowi[o][kx*4+ky];
                Tre[ky] += lr*c - li*s;
                Tim[ky] += lr*s + li*c;
            }
        }
        #pragma unroll
        for (int ky = 0; ky < 4; ++ky) { Tre[ky] *= inv32; Tim[ky] *= inv32; }
        for (int y = 0; y < 16; ++y) {
            float hsv = Tre[0];
            #pragma unroll
            for (int ky = 1; ky < 4; ++ky) {
                int idx = (2*ky*y) & 31;
                hsv += 2.f*(Tre[ky]*c32[idx] - Tim[ky]*s32[idx]);
            }
            hsv *= inv16;
            float z = hsv + nf[x*16 + y]*plo + cbo;
            acc += tanhf(z);
        }
    }
    acc += __shfl_down(acc, 4, 8);
    acc += __shfl_down(acc, 2, 8);
    acc += __shfl_down(acc, 1, 8);
    if ((t & 7) == 0) pooled_g[b*WIDTH + o] = acc * (1.0f/512.0f);
}

// ---------------------------------------------------------------------------
// Kernel 2: r-major gathered build. 256 threads: j = t&127, sub = t>>7.
// proj_W row segment in registers, reused over 128 samples per sub-half.
// Per-sample pooled vector hoisted via 8 x ds_read_b128 broadcast.
// ---------------------------------------------------------------------------
__global__ __launch_bounds__(256) void build_kernel(
    const float* __restrict__ M_base,
    const float* __restrict__ proj_W,
    const float* __restrict__ proj_b,
    const float* __restrict__ pooled_g,
    const signed char* __restrict__ pos_g,
    float* __restrict__ A_ws)
{
    __shared__ float pooled_l[256*WIDTH];   // 32 KB
    __shared__ signed char posl[256];

    const int r   = blockIdx.x >> 2;
    const int b0  = (blockIdx.x & 3) * 256;
    const int t   = threadIdx.x;
    const int j   = t & 127;
    const int sub = t >> 7;

    {
        const float4* src = (const float4*)(pooled_g + (size_t)b0*WIDTH);
        float4* dst = (float4*)pooled_l;
        for (int idx = t; idx < 256*WIDTH/4; idx += 256) dst[idx] = src[idx];
        if (t < 64) ((int*)posl)[t] = ((const int*)(pos_g + (size_t)r*BB + b0))[t];
    }

    float wj[WIDTH];
    #pragma unroll
    for (int o = 0; o < WIDTH; ++o) wj[o] = proj_W[(size_t)o*TOTAL + r*NF + j];
    const float base = M_base[r*NF + j] + proj_b[r*NF + j];
    __syncthreads();

    for (int bb = sub; bb < 256; bb += 2) {
        int pos = posl[bb];
        if (pos < 0) continue;
        const float4* pl4 = (const float4*)&pooled_l[bb*WIDTH];
        float4 p0 = pl4[0], p1 = pl4[1], p2 = pl4[2], p3 = pl4[3];
        float4 p4 = pl4[4], p5 = pl4[5], p6 = pl4[6], p7 = pl4[7];
        float acc = base;
        acc += p0.x*wj[0]  + p0.y*wj[1]  + p0.z*wj[2]  + p0.w*wj[3];
        acc += p1.x*wj[4]  + p1.y*wj[5]  + p1.z*wj[6]  + p1.w*wj[7];
        acc += p2.x*wj[8]  + p2.y*wj[9]  + p2.z*wj[10] + p2.w*wj[11];
        acc += p3.x*wj[12] + p3.y*wj[13] + p3.z*wj[14] + p3.w*wj[15];
        acc += p4.x*wj[16] + p4.y*wj[17] + p4.z*wj[18] + p4.w*wj[19];
        acc += p5.x*wj[20] + p5.y*wj[21] + p5.z*wj[22] + p5.w*wj[23];
        acc += p6.x*wj[24] + p6.y*wj[25] + p6.z*wj[26] + p6.w*wj[27];
        acc += p7.x*wj[28] + p7.y*wj[29] + p7.z*wj[30] + p7.w*wj[31];
        A_ws[((size_t)(b0+bb)*NF + pos)*NF + j] = acc;
    }
}

// ---------------------------------------------------------------------------
// Kernel 3: rank-8 LU, A in registers, ALL-WAVE REDUNDANT PIVOT (R14 proven).
// 512 threads, 8 waves: w=t>>6, l=t&63; half=w&1, q=w>>1; row i=l+64*half;
// owns cols q*32..q*32+31 (8 float4). Every wave runs the identical DPP
// pivot chain (no wave idles); per-thread coef back-sub for own row.
// 2 barriers/panel. Fast rcp (+1 NR) replaces IEEE divide on the chain.
// Output planar: out[b] = logabs, out[BB+b] = 0 or pi.
// ---------------------------------------------------------------------------
__global__ __launch_bounds__(512) void lu_kernel(
    const float* __restrict__ A_ws,
    float* __restrict__ out)
{
    __shared__ __align__(16) float pcolA[128*4];   // panel cols 0-3 (2 KB)
    __shared__ __align__(16) float pcolB[128*4];   // panel cols 4-7 (2 KB)
    __shared__ __align__(16) float Raw[8*128];     // pre-panel pivot rows (4 KB)
    __shared__ float pvbuf[128];
    __shared__ int   pivseq[128];

    const int t = threadIdx.x;
    const int l = t & 63;
    const int w = t >> 6;
    const int half = w & 1;
    const int q = w >> 1;
    const int i = l + 64*half;
    const int b = blockIdx.x;

    float4 Areg[8];
    {
        const float4* src = (const float4*)(A_ws + (size_t)b*(NF*NF) + i*NF + q*32);
        #pragma unroll
        for (int g = 0; g < 8; ++g) Areg[g] = src[g];
        if (q == 0) {
            *((float4*)&pcolA[i*4]) = Areg[0];
            *((float4*)&pcolB[i*4]) = Areg[1];
        }
    }
    bool done_i = false;
    bool done0 = false, done1 = false;   // per-lane retire masks (identical in all waves)
    __syncthreads();

    for (int p = 0; p < 16; ++p) {
        // ---------- all waves: redundant pivot chain on panel p ----------
        float4 a0v = *((const float4*)&pcolA[l*4]);
        float4 b0v = *((const float4*)&pcolB[l*4]);
        float4 a1v = *((const float4*)&pcolA[l*4 + 256]);
        float4 b1v = *((const float4*)&pcolB[l*4 + 256]);
        float v0[8] = { a0v.x,a0v.y,a0v.z,a0v.w, b0v.x,b0v.y,b0v.z,b0v.w };
        float v1[8] = { a1v.x,a1v.y,a1v.z,a1v.w, b1v.x,b1v.y,b1v.z,b1v.w };
        float lr0[8], lr1[8];
        int   prreg[8];

        #pragma unroll
        for (int k = 0; k < 8; ++k) {
            unsigned aa0 = __float_as_uint(v0[k]) & 0x7fffffffu;
            unsigned aa1 = __float_as_uint(v1[k]) & 0x7fffffffu;
            unsigned key0 = done0 ? 0u : ((aa0 & 0xffffff80u) | (unsigned)l);
            unsigned key1 = done1 ? 0u : ((aa1 & 0xffffff80u) | (unsigned)(l + 64));
            unsigned key = (key1 > key0) ? key1 : key0;
            DPP_UMAX(key, 0x111, 0xf);   // row_shr:1
            DPP_UMAX(key, 0x112, 0xf);   // row_shr:2
            DPP_UMAX(key, 0x114, 0xf);   // row_shr:4
            DPP_UMAX(key, 0x118, 0xf);   // row_shr:8
            DPP_UMAX(key, 0x142, 0xa);   // row_bcast:15
            DPP_UMAX(key, 0x143, 0xc);   // row_bcast:31
            const unsigned best = (unsigned)__builtin_amdgcn_readlane((int)key, 63);
            const int row = (int)(best & 127u);
            const int lw  = row & 63;
            const bool lowh = (row < 64);
            const float pv = lowh ? readlanef(v0[k], lw) : readlanef(v1[k], lw);
            prreg[k] = row;
            const float inv = frcp_fast(pv);
            float l0 = (done0 || row == l)      ? 0.f : v0[k] * inv;
            float l1 = (done1 || row == l + 64) ? 0.f : v1[k] * inv;
            lr0[k] = l0; lr1[k] = l1;
            if (row == l)      done0 = true;
            if (row == l + 64) done1 = true;
            #pragma unroll
            for (int j = 0; j < 8; ++j) if (j > k) {
                float ukj = lowh ? readlanef(v0[j], lw) : readlanef(v1[j], lw);
                v0[j] -= l0 * ukj;
                v1[j] -= l1 * ukj;
            }
            if (w == 0 && l == 0) { pivseq[8*p+k] = row; pvbuf[8*p+k] = pv; }
        }

        // ---------- per-thread coefs for OWN row (back-sub, Lt fused) ----------
        float cs[8];
        {
            float lm[8];
            #pragma unroll
            for (int s = 0; s < 8; ++s) lm[s] = half ? lr1[s] : lr0[s];
            #pragma unroll
            for (int s2 = 7; s2 >= 0; --s2) {
                float acc = -lm[s2];
                #pragma unroll
                for (int sp = 7; sp > 0; --sp) if (sp > s2) {
                    float Lt = (prreg[sp] < 64) ? readlanef(lr0[s2], prreg[sp])
                                                : readlanef(lr1[s2], prreg[sp] - 64);
                    acc -= cs[sp] * Lt;
                }
                cs[s2] = acc;
            }
        }

        // ---------- pivot-row owners publish Raw (pre-panel values) ----------
        int fp = -1;
        #pragma unroll
        for (int s = 0; s < 8; ++s) if (i == prreg[s]) fp = s;
        if (fp >= 0) {
            #pragma unroll
            for (int g = 0; g < 8; ++g)
                *((float4*)&Raw[fp*128 + (q*8 + g)*4]) = Areg[g];
        }
        __syncthreads();   // barrier 1: Raw ready

        // ---------- rank-8 update of own row + publish pcol(p+1) ----------
        if (fp >= 0) {
            done_i = true;   // retired; trailing values never read again
        } else if (!done_i) {
            #pragma unroll
            for (int g = 0; g < 8; ++g) {
                const int G = q*8 + g;
                if (G > 2*p + 1) {
                    const int cbase = G*4;
                    float4 own = Areg[g];
                    #pragma unroll
                    for (int s = 0; s < 8; ++s) {
                        const float4 rv = *((const float4*)&Raw[s*128 + cbase]);
                        own.x += cs[s]*rv.x; own.y += cs[s]*rv.y;
                        own.z += cs[s]*rv.z; own.w += cs[s]*rv.w;
                    }
                    Areg[g] = own;
                    if (G == 2*p + 2) *((float4*)&pcolA[i*4]) = own;
                    if (G == 2*p + 3) *((float4*)&pcolB[i*4]) = own;
                }
            }
        }
        __syncthreads();   // barrier 2: Areg stable + pcol(p+1) ready
    }

    // ---------- logabs + sign (wave 0) ----------
    if (w == 0) {
        float d0 = pvbuf[l], d1 = pvbuf[l + 64];
        int   ps0 = pivseq[l], ps1 = pivseq[l + 64];
        float ls = logf(fabsf(d0)) + logf(fabsf(d1));
        int neg = ((d0 < 0.f) ? 1 : 0) ^ ((d1 < 0.f) ? 1 : 0);
        #pragma unroll
        for (int off = 32; off > 0; off >>= 1) {
            ls  += __shfl_xor(ls,  off, 64);
            neg ^= __shfl_xor(neg, off, 64);
        }
        unsigned long long vis0 = 0ull, vis1 = 0ull;
        int trans = 0;
        for (int k = 0; k < 128; ++k) {
            bool vk = (k < 64) ? ((vis0 >> k) & 1ull) : ((vis1 >> (k - 64)) & 1ull);
            if (!vk) {
                int j = k, len = 0;
                while (true) {
                    bool vj = (j < 64) ? ((vis0 >> j) & 1ull) : ((vis1 >> (j - 64)) & 1ull);
                    if (vj) break;
                    if (j < 64) vis0 |= (1ull << j); else vis1 |= (1ull << (j - 64));
                    j = (j < 64) ? __builtin_amdgcn_readlane(ps0, j)
                                 : __builtin_amdgcn_readlane(ps1, j - 64);
                    ++len;
                }
                trans += len - 1;
            }
        }
        if (l == 0) {
            int parity = (neg ^ (trans & 1)) & 1;
            out[b]      = ls;
            out[BB + b] = parity ? (float)M_PI : 0.0f;
        }
    }
}

// ---------------------------------------------------------------------------
extern "C" void kernel_launch(void* const* d_in, const int* in_sizes, int n_in,
                              void* d_out, int out_size, void* d_ws, size_t ws_size,
                              hipStream_t stream) {
    const int*   n       = (const int*)  d_in[0];
    const float* M_base  = (const float*)d_in[1];
    const float* lift_W  = (const float*)d_in[2];
    const float* lift_b  = (const float*)d_in[3];
    const float* spec_Wr = (const float*)d_in[4];
    const float* spec_Wi = (const float*)d_in[5];
    const float* pw_W    = (const float*)d_in[6];
    const float* pw_b    = (const float*)d_in[7];
    const float* proj_W  = (const float*)d_in[8];
    const float* proj_b  = (const float*)d_in[9];

    // ws layout: pooled 128KB | pos 512KB | (align 1MB) A_ws 64MB
    float*       pooled = (float*)d_ws;
    signed char* pos    = (signed char*)((char*)d_ws + 128*1024);
    float*       A_ws   = (float*)((char*)d_ws + (1 << 20));

    fno_pooled_kernel<<<BB, 256, 0, stream>>>(n, lift_W, lift_b, spec_Wr, spec_Wi,
                                              pw_W, pw_b, pooled, pos);
    build_kernel<<<SIZE*4, 256, 0, stream>>>(M_base, proj_W, proj_b, pooled, pos, A_ws);
    lu_kernel<<<BB, 512, 0, stream>>>(A_ws, (float*)d_out);
}